// Round 1
// baseline (418.651 us; speedup 1.0000x reference)
//
#include <hip/hip_runtime.h>
#include <hip/hip_bf16.h>
#include <math.h>

#define BATCH   2
#define N_NODES 10000
#define E_EDGES 160000
#define BN      (BATCH * N_NODES)       // 20000
#define BE      (BATCH * E_EDGES)       // 320000
#define ND      128
#define ED      64
#define HID     256
#define K1      320   // 2*ND + ED
#define K2      256
#define K1U     384   // ND + HID
#define NOUT    128
#define TM      64    // node-kernel rows per block
#define TME     64    // edge-kernel rows per block (was 128; halved for 2 blocks/CU)
#define LDA     40    // node-kernel A stride (bf16)
#define LDB     40    // node-kernel B stride (bf16)
#define LDH     264   // H stride (bf16), 256+8
#define SCAN_BLOCKS ((BN + 1023) / 1024)   // 20

typedef __attribute__((ext_vector_type(8))) short bf16x8;
typedef __attribute__((ext_vector_type(4))) float f32x4;

// fast tanh-gelu: tanh(u) = 1 - 2/(exp(2u)+1); both tails saturate correctly.
__device__ __forceinline__ float gelu_tanh(float x) {
    float u = 0.7978845608028654f * (x + 0.044715f * x * x * x);
    float e = __expf(2.0f * u);
    float t = 1.0f - 2.0f * __builtin_amdgcn_rcpf(e + 1.0f);
    return 0.5f * x * (1.0f + t);
}

__device__ __forceinline__ unsigned short f2bf(float f) {
    __hip_bfloat16 h = __float2bfloat16(f);
    return *reinterpret_cast<unsigned short*>(&h);
}

__device__ __forceinline__ float bf2f(unsigned short u) {
    unsigned int x = ((unsigned int)u) << 16;
    return *reinterpret_cast<float*>(&x);
}

// async global->LDS DMA, 16 B per lane; lds dest = wave-uniform base + lane*16
__device__ __forceinline__ void gl2lds16(const void* g, void* l) {
    __builtin_amdgcn_global_load_lds(
        (const __attribute__((address_space(1))) unsigned int*)g,
        (__attribute__((address_space(3))) unsigned int*)l,
        16, 0, 0);
}

// ---------- prep kernels ----------

__global__ __launch_bounds__(256) void f32_to_bf16_vec(
    const float* __restrict__ in, unsigned short* __restrict__ out, int n4)
{
    int i = blockIdx.x * blockDim.x + threadIdx.x;
    if (i < n4) {
        float4 v = ((const float4*)in)[i];
        ushort4 o;
        o.x = f2bf(v.x); o.y = f2bf(v.y); o.z = f2bf(v.z); o.w = f2bf(v.w);
        ((ushort4*)out)[i] = o;
    }
}

__global__ __launch_bounds__(256) void w_transpose_bf16(
    const float* __restrict__ w, unsigned short* __restrict__ wt, int K, int N)
{
    int id = blockIdx.x * blockDim.x + threadIdx.x;
    if (id < K * N) {
        int k = id % K;
        int n = id / K;
        wt[id] = f2bf(w[k * N + n]);
    }
}

__global__ __launch_bounds__(256) void dst_hist(
    const int* __restrict__ eidx, int* __restrict__ hist)
{
    int e = blockIdx.x * blockDim.x + threadIdx.x;
    if (e < BE) {
        int dst = eidx[2 * e + 1];
        int b   = e / E_EDGES;
        atomicAdd(&hist[b * N_NODES + dst], 1);
    }
}

// ---------- hierarchical scan ----------

__global__ __launch_bounds__(1024) void scan_partial(
    const int* __restrict__ hist, int* __restrict__ offs, int* __restrict__ bsum)
{
    __shared__ int buf[1024];
    int tid = threadIdx.x;
    int i   = blockIdx.x * 1024 + tid;
    int v   = (i < BN) ? hist[i] : 0;
    buf[tid] = v;
    __syncthreads();
    #pragma unroll
    for (int d = 1; d < 1024; d <<= 1) {
        int t = (tid >= d) ? buf[tid - d] : 0;
        __syncthreads();
        buf[tid] += t;
        __syncthreads();
    }
    int incl = buf[tid];
    if (i < BN) offs[i] = incl - v;
    if (tid == 1023) bsum[blockIdx.x] = incl;
}

__global__ __launch_bounds__(64) void scan_sums(int* __restrict__ bsum)
{
    if (threadIdx.x == 0) {
        int acc = 0;
        for (int b = 0; b < SCAN_BLOCKS; ++b) {
            int t = bsum[b];
            bsum[b] = acc;
            acc += t;
        }
    }
}

__global__ __launch_bounds__(1024) void scan_add(
    int* __restrict__ offs, const int* __restrict__ bsum)
{
    int i = blockIdx.x * 1024 + threadIdx.x;
    if (i < BN) offs[i] += bsum[blockIdx.x];
}

__global__ __launch_bounds__(256) void dst_scatter(
    const int* __restrict__ eidx, int* __restrict__ offs, int* __restrict__ perm)
{
    int e = blockIdx.x * blockDim.x + threadIdx.x;
    if (e < BE) {
        int dst  = eidx[2 * e + 1];
        int b    = e / E_EDGES;
        int pos  = atomicAdd(&offs[b * N_NODES + dst], 1);
        perm[pos] = e;
    }
}

// ---------- edge MLP (MFMA, 64 rows/block, 2 blocks/CU, barrier-free K-loops) ----------
// LDS 74,752 B (+768 idx) -> 2 blocks/CU on 160 KiB:
//   sA   [0 .. 32,768)        8 panels x [64 rows x 32 k] bf16 (node features)
//   sE   [32,768 .. 40,960)   2 panels x [64 rows x 32 k] bf16 (edge features)
//   sH   [40,960 .. 74,752)   64 x 264 bf16
// Weights (W1t/W2t, n-major) are loaded straight global->VGPR per k-step with
// one-step prefetch: no sB LDS slice, no per-step vmcnt(0) drain.
#define SMEM_A  0
#define SMEM_E  32768
#define SMEM_H  40960
#define EDGE_SMEM 74752

__global__ __launch_bounds__(512, 4) void edge_mlp_mfma(
    const unsigned short* __restrict__ nodef_bf,
    const int*            __restrict__ eidx,
    const float*          __restrict__ edgef,
    const int*            __restrict__ perm,
    const unsigned short* __restrict__ w1t,       // [256][320] bf16 n-major
    const float*          __restrict__ b1m,
    const unsigned short* __restrict__ w2t,       // [256][256] bf16 n-major
    const float*          __restrict__ b2m,
    float* __restrict__ agg)
{
    __shared__ __align__(16) char smem[EDGE_SMEM];
    unsigned short* sH = (unsigned short*)(smem + SMEM_H);
    unsigned short* sE = (unsigned short*)(smem + SMEM_E);
    __shared__ int s_src[TME];
    __shared__ int s_dst[TME];
    __shared__ int s_eid[TME];

    const int tid  = threadIdx.x;
    const int wave = tid >> 6;
    const int lane = tid & 63;
    const int quad = lane >> 4;
    const int r16  = lane & 15;
    const int be0  = blockIdx.x * TME;

    if (tid < TME) {
        int eid = perm[be0 + tid];
        int b   = eid / E_EDGES;
        int2 se = ((const int2*)eidx)[eid];
        s_eid[tid] = eid;
        s_src[tid] = b * N_NODES + se.x;
        s_dst[tid] = b * N_NODES + se.y;
    }
    __syncthreads();

    // ---- stage ALL of A once ----
    // node panels (k 0..255): 32 KB via DMA, 4 insts/wave; panel p == wave
    #pragma unroll
    for (int j = 0; j < 4; ++j) {
        int er = j * 16 + (lane >> 2);  // edge row 0..63
        int c8 = (lane & 3) * 8;
        const unsigned short* gs = (wave < 4)
            ? nodef_bf + (size_t)s_src[er] * ND + wave * 32 + c8
            : nodef_bf + (size_t)s_dst[er] * ND + (wave - 4) * 32 + c8;
        gl2lds16(gs, smem + SMEM_A + wave * 4096 + j * 1024);
    }
    // edge panels (k 256..319): fp32 -> bf16 manual; 512 threads x 8 floats
    {
        int row = tid >> 3;
        int c0  = (tid & 7) * 8;        // 0..56
        const float* fp = edgef + (size_t)s_eid[row] * ED + c0;
        float4 v0 = *(const float4*)fp;
        float4 v1 = *(const float4*)(fp + 4);
        ushort4 o0, o1;
        o0.x = f2bf(v0.x); o0.y = f2bf(v0.y); o0.z = f2bf(v0.z); o0.w = f2bf(v0.w);
        o1.x = f2bf(v1.x); o1.y = f2bf(v1.y); o1.z = f2bf(v1.z); o1.w = f2bf(v1.w);
        int p2 = c0 >> 5, kk = c0 & 31;
        *(ushort4*)&sE[p2 * 2048 + row * 32 + kk]     = o0;
        *(ushort4*)&sE[p2 * 2048 + row * 32 + kk + 4] = o1;
    }
    __syncthreads();   // drains DMA (vmcnt0 at barrier) + LDS writes

    f32x4 acc[4][2];
    #pragma unroll
    for (int mt = 0; mt < 4; ++mt)
        #pragma unroll
        for (int nt = 0; nt < 2; ++nt)
            acc[mt][nt] = (f32x4){0.f, 0.f, 0.f, 0.f};

    // ---- Layer 1: K=320, 10 k-steps, NO barriers, B global->VGPR prefetch ----
    {
        const unsigned short* wB = w1t + (size_t)(wave * 32) * K1;
        bf16x8 bc0 = *(const bf16x8*)&wB[(size_t)r16        * K1 + quad * 8];
        bf16x8 bc1 = *(const bf16x8*)&wB[(size_t)(16 + r16) * K1 + quad * 8];
        #pragma unroll
        for (int ks = 0; ks < K1 / 32; ++ks) {
            bf16x8 bn0 = bc0, bn1 = bc1;
            if (ks + 1 < K1 / 32) {
                bn0 = *(const bf16x8*)&wB[(size_t)r16        * K1 + (ks + 1) * 32 + quad * 8];
                bn1 = *(const bf16x8*)&wB[(size_t)(16 + r16) * K1 + (ks + 1) * 32 + quad * 8];
            }
            const unsigned short* pA = (ks < 8)
                ? (const unsigned short*)(smem + SMEM_A) + ks * 2048
                : sE + (ks - 8) * 2048;
            bf16x8 af[4];
            #pragma unroll
            for (int mt = 0; mt < 4; ++mt)
                af[mt] = *(const bf16x8*)&pA[(mt * 16 + r16) * 32 + quad * 8];
            #pragma unroll
            for (int mt = 0; mt < 4; ++mt) {
                acc[mt][0] = __builtin_amdgcn_mfma_f32_16x16x32_bf16(
                    af[mt], bc0, acc[mt][0], 0, 0, 0);
                acc[mt][1] = __builtin_amdgcn_mfma_f32_16x16x32_bf16(
                    af[mt], bc1, acc[mt][1], 0, 0, 0);
            }
            bc0 = bn0; bc1 = bn1;
        }
    }

    // ---- layer-1 epilogue -> sH (sH disjoint from sA/sE; no barrier needed) ----
    #pragma unroll
    for (int nt = 0; nt < 2; ++nt) {
        int n = wave * 32 + nt * 16 + r16;
        float bias = b1m[n];
        #pragma unroll
        for (int mt = 0; mt < 4; ++mt) {
            #pragma unroll
            for (int r = 0; r < 4; ++r) {
                int m = mt * 16 + quad * 4 + r;
                sH[m * LDH + n] = f2bf(gelu_tanh(acc[mt][nt][r] + bias));
            }
            acc[mt][nt] = (f32x4){0.f, 0.f, 0.f, 0.f};
        }
    }
    __syncthreads();   // sH visible to all waves

    // ---- Layer 2: K=256, 8 k-steps, NO barriers, B global->VGPR prefetch ----
    {
        const unsigned short* wB = w2t + (size_t)(wave * 32) * K2;
        bf16x8 bc0 = *(const bf16x8*)&wB[(size_t)r16        * K2 + quad * 8];
        bf16x8 bc1 = *(const bf16x8*)&wB[(size_t)(16 + r16) * K2 + quad * 8];
        #pragma unroll
        for (int ks = 0; ks < K2 / 32; ++ks) {
            bf16x8 bn0 = bc0, bn1 = bc1;
            if (ks + 1 < K2 / 32) {
                bn0 = *(const bf16x8*)&wB[(size_t)r16        * K2 + (ks + 1) * 32 + quad * 8];
                bn1 = *(const bf16x8*)&wB[(size_t)(16 + r16) * K2 + (ks + 1) * 32 + quad * 8];
            }
            bf16x8 af[4];
            #pragma unroll
            for (int mt = 0; mt < 4; ++mt)
                af[mt] = *(const bf16x8*)&sH[(mt * 16 + r16) * LDH + ks * 32 + quad * 8];
            #pragma unroll
            for (int mt = 0; mt < 4; ++mt) {
                acc[mt][0] = __builtin_amdgcn_mfma_f32_16x16x32_bf16(
                    af[mt], bc0, acc[mt][0], 0, 0, 0);
                acc[mt][1] = __builtin_amdgcn_mfma_f32_16x16x32_bf16(
                    af[mt], bc1, acc[mt][1], 0, 0, 0);
            }
            bc0 = bn0; bc1 = bn1;
        }
    }
    __syncthreads();   // all waves done reading sH before fb overwrite

    // ---- epilogue: C2(+bias) -> fb (bf16, aliases sH), run-reduce ----
    unsigned short* fb = sH;
    #pragma unroll
    for (int nt = 0; nt < 2; ++nt) {
        int n = wave * 32 + nt * 16 + r16;
        float bias = b2m[n];
        #pragma unroll
        for (int mt = 0; mt < 4; ++mt) {
            #pragma unroll
            for (int r = 0; r < 4; ++r) {
                int m = mt * 16 + quad * 4 + r;
                fb[m * LDH + n] = f2bf(acc[mt][nt][r] + bias);
            }
        }
    }
    __syncthreads();

    {
        const int cc = tid & 255;          // column
        const int r0 = (tid >> 8) * 32;    // row-half base
        int   cur  = s_dst[r0];
        float racc = 0.f;
        for (int mb = 0; mb < 32; mb += 8) {
            float v[8];
            #pragma unroll
            for (int j = 0; j < 8; ++j)
                v[j] = bf2f(fb[(r0 + mb + j) * LDH + cc]);
            #pragma unroll
            for (int j = 0; j < 8; ++j) {
                int d = s_dst[r0 + mb + j];
                if (d != cur) {
                    atomicAdd(&agg[(size_t)cur * HID + cc], racc);
                    cur = d; racc = v[j];
                } else {
                    racc += v[j];
                }
            }
        }
        atomicAdd(&agg[(size_t)cur * HID + cc], racc);
    }
}

// ---------- node MLP (MFMA) ----------

template <bool PRET>
__global__ __launch_bounds__(256) void node_mlp_mfma(
    const float* __restrict__ nodef,
    const float* __restrict__ agg,
    const float* __restrict__ W1u,
    const unsigned short* __restrict__ w1ut,
    const float* __restrict__ b1u,
    const float* __restrict__ W2u,
    const unsigned short* __restrict__ w2ut,
    const float* __restrict__ b2u,
    float* __restrict__ out)
{
    __shared__ __align__(16) unsigned short sA[TM * LDA];
    __shared__ __align__(16) unsigned short sB[HID * LDB];
    __shared__ __align__(16) unsigned short sH[TM * LDH];

    const int tid  = threadIdx.x;
    const int wave = tid >> 6;
    const int lane = tid & 63;
    const int quad = lane >> 4;
    const int r16  = lane & 15;
    const int n0   = blockIdx.x * TM;

    f32x4 acc[4][4];
    #pragma unroll
    for (int mt = 0; mt < 4; ++mt)
        #pragma unroll
        for (int nt = 0; nt < 4; ++nt)
            acc[mt][nt] = (f32x4){0.f, 0.f, 0.f, 0.f};

    for (int ks = 0; ks < K1U / 32; ++ks) {
        const int k0 = ks * 32;
        {
            int e  = tid >> 2, c = tid & 3;
            int row = n0 + e; if (row >= BN) row = BN - 1;
            int kk = k0 + c * 8;
            const float* fp = (kk < 128)
                ? nodef + (size_t)row * ND + kk
                : agg   + (size_t)row * HID + (kk - 128);
            float4 v0 = *(const float4*)fp;
            float4 v1 = *(const float4*)(fp + 4);
            ushort4 o0, o1;
            o0.x = f2bf(v0.x); o0.y = f2bf(v0.y); o0.z = f2bf(v0.z); o0.w = f2bf(v0.w);
            o1.x = f2bf(v1.x); o1.y = f2bf(v1.y); o1.z = f2bf(v1.z); o1.w = f2bf(v1.w);
            *(ushort4*)&sA[e * LDA + c * 8]     = o0;
            *(ushort4*)&sA[e * LDA + c * 8 + 4] = o1;
        }
        if (PRET) {
            #pragma unroll
            for (int ci = 0; ci < 4; ++ci) {
                int c = tid + ci * 256;
                int n = c >> 2, sub = c & 3;
                *(float4*)&sB[n * LDB + sub * 8] =
                    *(const float4*)&w1ut[(size_t)n * K1U + k0 + sub * 8];
            }
        } else {
            #pragma unroll
            for (int it = 0; it < 4; ++it) {
                int u  = it * 256 + tid;
                int kp = u & 15;
                int nq = u >> 4;
                int k  = k0 + 2 * kp;
                float4 v0 = *(const float4*)&W1u[(size_t)k * HID + 4 * nq];
                float4 v1 = *(const float4*)&W1u[(size_t)(k + 1) * HID + 4 * nq];
                const float* a0 = (const float*)&v0;
                const float* a1 = (const float*)&v1;
                #pragma unroll
                for (int j = 0; j < 4; ++j) {
                    unsigned int pk = (unsigned int)f2bf(a0[j]) |
                                      ((unsigned int)f2bf(a1[j]) << 16);
                    *(unsigned int*)&sB[(4 * nq + j) * LDB + 2 * kp] = pk;
                }
            }
        }
        __syncthreads();

        bf16x8 af[4], bfg[4];
        #pragma unroll
        for (int mt = 0; mt < 4; ++mt)
            af[mt] = *(const bf16x8*)&sA[(mt * 16 + r16) * LDA + quad * 8];
        #pragma unroll
        for (int nt = 0; nt < 4; ++nt)
            bfg[nt] = *(const bf16x8*)&sB[(wave * 64 + nt * 16 + r16) * LDB + quad * 8];
        #pragma unroll
        for (int mt = 0; mt < 4; ++mt)
            #pragma unroll
            for (int nt = 0; nt < 4; ++nt)
                acc[mt][nt] = __builtin_amdgcn_mfma_f32_16x16x32_bf16(
                    af[mt], bfg[nt], acc[mt][nt], 0, 0, 0);
        __syncthreads();
    }

    #pragma unroll
    for (int nt = 0; nt < 4; ++nt) {
        int n = wave * 64 + nt * 16 + r16;
        float bias = b1u[n];
        #pragma unroll
        for (int mt = 0; mt < 4; ++mt) {
            #pragma unroll
            for (int r = 0; r < 4; ++r) {
                int m = mt * 16 + quad * 4 + r;
                sH[m * LDH + n] = f2bf(gelu_tanh(acc[mt][nt][r] + bias));
            }
        }
    }

    f32x4 acc2[4][2];
    #pragma unroll
    for (int mt = 0; mt < 4; ++mt)
        #pragma unroll
        for (int nt = 0; nt < 2; ++nt)
            acc2[mt][nt] = (f32x4){0.f, 0.f, 0.f, 0.f};

    for (int ks = 0; ks < K2 / 32; ++ks) {
        const int k0 = ks * 32;
        if (PRET) {
            #pragma unroll
            for (int it = 0; it < 2; ++it) {
                int c = it * 256 + tid;
                int n = c >> 2, sub = c & 3;
                *(float4*)&sB[n * LDB + sub * 8] =
                    *(const float4*)&w2ut[(size_t)n * K2 + k0 + sub * 8];
            }
        } else {
            #pragma unroll
            for (int it = 0; it < 2; ++it) {
                int u  = it * 256 + tid;
                int kp = u & 15;
                int nq = u >> 4;
                int k  = k0 + 2 * kp;
                float4 v0 = *(const float4*)&W2u[(size_t)k * NOUT + 4 * nq];
                float4 v1 = *(const float4*)&W2u[(size_t)(k + 1) * NOUT + 4 * nq];
                const float* a0 = (const float*)&v0;
                const float* a1 = (const float*)&v1;
                #pragma unroll
                for (int j = 0; j < 4; ++j) {
                    unsigned int pk = (unsigned int)f2bf(a0[j]) |
                                      ((unsigned int)f2bf(a1[j]) << 16);
                    *(unsigned int*)&sB[(4 * nq + j) * LDB + 2 * kp] = pk;
                }
            }
        }
        __syncthreads();

        bf16x8 af[4], bfg[2];
        #pragma unroll
        for (int mt = 0; mt < 4; ++mt)
            af[mt] = *(const bf16x8*)&sH[(mt * 16 + r16) * LDH + k0 + quad * 8];
        #pragma unroll
        for (int nt = 0; nt < 2; ++nt)
            bfg[nt] = *(const bf16x8*)&sB[(wave * 32 + nt * 16 + r16) * LDB + quad * 8];
        #pragma unroll
        for (int mt = 0; mt < 4; ++mt)
            #pragma unroll
            for (int nt = 0; nt < 2; ++nt)
                acc2[mt][nt] = __builtin_amdgcn_mfma_f32_16x16x32_bf16(
                    af[mt], bfg[nt], acc2[mt][nt], 0, 0, 0);
        __syncthreads();
    }

    #pragma unroll
    for (int nt = 0; nt < 2; ++nt) {
        int n = wave * 32 + nt * 16 + r16;
        float bias = b2u[n];
        #pragma unroll
        for (int mt = 0; mt < 4; ++mt) {
            #pragma unroll
            for (int r = 0; r < 4; ++r) {
                int m = mt * 16 + quad * 4 + r;
                if (n0 + m < BN)
                    out[(size_t)(n0 + m) * NOUT + n] = acc2[mt][nt][r] + bias;
            }
        }
    }
}

// ---------- launch ----------
// ws: agg [0 .. 20,480,000) proven; node weights in ws iff headroom.
// d_out stash (read only before node_mlp_mfma runs):
//   nodef_bf [0 .. 5,120,000)
//   w1t      [5,120,000 .. 5,283,840)
//   w2t      [5,283,840 .. 5,414,912)
//   hist     [5,414,912 .. 5,494,912)
//   offs     [5,494,912 .. 5,574,912)
//   perm     [5,574,912 .. 6,854,912)
//   bsum     [6,854,912 .. 6,855,040)   total < 10,240,000 B

extern "C" void kernel_launch(void* const* d_in, const int* in_sizes, int n_in,
                              void* d_out, int out_size, void* d_ws, size_t ws_size,
                              hipStream_t stream) {
    const float* nodef = (const float*)d_in[0];
    const int*   eidx  = (const int*)  d_in[1];
    const float* edgef = (const float*)d_in[2];
    const float* W1m   = (const float*)d_in[3];
    const float* b1m   = (const float*)d_in[4];
    const float* W2m   = (const float*)d_in[5];
    const float* b2m   = (const float*)d_in[6];
    const float* W1u   = (const float*)d_in[7];
    const float* b1u   = (const float*)d_in[8];
    const float* W2u   = (const float*)d_in[9];
    const float* b2u   = (const float*)d_in[10];
    float* out = (float*)d_out;

    char* wsb = (char*)d_ws;
    float* agg = (float*)wsb;

    const size_t AGG_B  = (size_t)BN * HID * sizeof(float);
    const size_t W1UT_B = (size_t)K1U * HID * sizeof(unsigned short);
    const size_t W2UT_B = (size_t)K2 * NOUT * sizeof(unsigned short);
    const bool ws_pret = ws_size >= AGG_B + W1UT_B + W2UT_B;

    char* ob = (char*)d_out;
    unsigned short* nodef_bf = (unsigned short*)ob;
    unsigned short* w1t  = (unsigned short*)(ob + 5120000);
    unsigned short* w2t  = (unsigned short*)(ob + 5283840);
    int* hist            = (int*)(ob + 5414912);
    int* offs            = (int*)(ob + 5494912);
    int* perm            = (int*)(ob + 5574912);
    int* bsum            = (int*)(ob + 6854912);

    hipMemsetAsync(agg, 0, AGG_B, stream);
    hipMemsetAsync(hist, 0, BN * sizeof(int), stream);

    {
        int n4 = BN * ND / 4;
        f32_to_bf16_vec<<<(n4 + 255) / 256, 256, 0, stream>>>(nodef, nodef_bf, n4);
    }
    w_transpose_bf16<<<(K1 * HID + 255) / 256, 256, 0, stream>>>(W1m, w1t, K1, HID);
    w_transpose_bf16<<<(K2 * HID + 255) / 256, 256, 0, stream>>>(W2m, w2t, K2, HID);

    dst_hist<<<(BE + 255) / 256, 256, 0, stream>>>(eidx, hist);
    scan_partial<<<SCAN_BLOCKS, 1024, 0, stream>>>(hist, offs, bsum);
    scan_sums<<<1, 64, 0, stream>>>(bsum);
    scan_add<<<SCAN_BLOCKS, 1024, 0, stream>>>(offs, bsum);
    dst_scatter<<<(BE + 255) / 256, 256, 0, stream>>>(eidx, offs, perm);

    edge_mlp_mfma<<<BE / TME, 512, 0, stream>>>(
        nodef_bf, eidx, edgef, perm, w1t, b1m, w2t, b2m, agg);

    if (ws_pret) {
        unsigned short* w1ut = (unsigned short*)(wsb + AGG_B);
        unsigned short* w2ut = (unsigned short*)(wsb + AGG_B + W1UT_B);
        w_transpose_bf16<<<(K1U * HID + 255) / 256, 256, 0, stream>>>(W1u, w1ut, K1U, HID);
        w_transpose_bf16<<<(K2 * NOUT + 255) / 256, 256, 0, stream>>>(W2u, w2ut, K2, NOUT);
        node_mlp_mfma<true><<<(BN + TM - 1) / TM, 256, 0, stream>>>(
            nodef, agg, nullptr, w1ut, b1u, nullptr, w2ut, b2u, out);
    } else {
        node_mlp_mfma<false><<<(BN + TM - 1) / TM, 256, 0, stream>>>(
            nodef, agg, W1u, nullptr, b1u, W2u, nullptr, b2u, out);
    }
}